// Round 1
// baseline (1374.849 us; speedup 1.0000x reference)
//
#include <hip/hip_runtime.h>
#include <cstdint>
#include <cstddef>

#define GN   16384
#define GIN  128
#define GOUT 64
#define NCH  8          // column chunks
#define LOG2E 1.44269504088896340736f

typedef __attribute__((ext_vector_type(8))) short short8;
typedef __attribute__((ext_vector_type(4))) float f32x4;
typedef __attribute__((ext_vector_type(4))) int   int4v;

__device__ __forceinline__ unsigned short f2bf(float f) {
  unsigned u = __float_as_uint(f);
  return (unsigned short)((u + 0x8000u) >> 16);   // round-half-up (cheap)
}

__device__ __forceinline__ unsigned short f2bf_rne(float f) {
  unsigned u = __float_as_uint(f);
  u += 0x7FFFu + ((u >> 16) & 1u);
  return (unsigned short)(u >> 16);
}

// ---------------------------------------------------------------------------
// prep (verified R5 version): Wh = x@W, f_src/f_dst (x log2e), Wh packed in
// MFMA B-fragment order: wpk[col_tile(512)][frag(4)][lane(64)][t(8)] bf16,
// col = col_tile*32 + (lane>>4)*8 + t, out-dim d = frag*16 + (lane&15).
// ---------------------------------------------------------------------------
__global__ __launch_bounds__(256) void prep_kernel(
    const float* __restrict__ x, const float* __restrict__ w,
    const float* __restrict__ aw, unsigned short* __restrict__ wpk,
    float* __restrict__ fs2, float* __restrict__ fd2)
{
  __shared__ float ws[GIN * GOUT];          // 32 KB
  __shared__ float red[2][64][4];

  const int t = threadIdx.x;
  const int rb = blockIdx.x * 64;

  for (int i = t; i < (GIN * GOUT) / 4; i += 256)
    ((float4*)ws)[i] = ((const float4*)w)[i];
  __syncthreads();

  const int r = t & 63, s = t >> 6;
  const int row = rb + r;
  const float* xr = x + (size_t)row * GIN;

  float acc[16];
#pragma unroll
  for (int d = 0; d < 16; ++d) acc[d] = 0.f;

  for (int kk = 0; kk < GIN; kk += 4) {
    float4 xv = *(const float4*)(xr + kk);
    float xa[4] = {xv.x, xv.y, xv.z, xv.w};
#pragma unroll
    for (int u = 0; u < 4; ++u) {
#pragma unroll
      for (int d = 0; d < 16; ++d)
        acc[d] += xa[u] * ws[(kk + u) * GOUT + s * 16 + d];
    }
  }

  const int jc = row >> 5;
  const int qq = (row & 31) >> 3;
  const int tt = row & 7;
  float psrc = 0.f, pdst = 0.f;
#pragma unroll
  for (int d = 0; d < 16; ++d) {
    const int dg = s * 16 + d;
    psrc += acc[d] * aw[dg];
    pdst += acc[d] * aw[GOUT + dg];
    const int f = dg >> 4, n = dg & 15;
    wpk[(size_t)jc * 4096 + f * 1024 + (qq * 16 + n) * 8 + tt] = f2bf_rne(acc[d]);
  }
  red[0][r][s] = psrc;
  red[1][r][s] = pdst;
  __syncthreads();
  if (s == 0) {
    float a_ = red[0][r][0] + red[0][r][1] + red[0][r][2] + red[0][r][3];
    float b_ = red[1][r][0] + red[1][r][1] + red[1][r][2] + red[1][r][3];
    fs2[row] = a_ * LOG2E;
    fd2[row] = b_ * LOG2E;
  }
}

// ---------------------------------------------------------------------------
// main v7: R5 numeric path (direct exp2 p, bf16 pack), restructured:
//  - 64 rows per wave (4 A-fragments share each B-fragment load)
//  - NO atomics: per-chunk partial slabs, reduced in fin_kernel
// One wave per (64 rows, 1/8 col chunk) = 2048 waves (all co-resident).
// ---------------------------------------------------------------------------
__global__ __launch_bounds__(256) void gat_main(
    const int* __restrict__ adj, const unsigned short* __restrict__ wpk,
    const float* __restrict__ fs2, const float* __restrict__ fd2,
    float* __restrict__ nump, float* __restrict__ denp)
{
  const int wave  = blockIdx.x * 4 + (threadIdx.x >> 6);
  const int lane  = threadIdx.x & 63;
  const int strip = wave & 255;             // 256 strips of 64 rows
  const int chunk = wave >> 8;              // 8 column chunks
  const int m = lane & 15;
  const int q = lane >> 4;

  int   row[4];
  float fs[4];
  const int4v* __restrict__ arow[4];
#pragma unroll
  for (int g = 0; g < 4; ++g) {
    row[g] = strip * 64 + g * 16 + m;
    fs[g] = fs2[row[g]];
    arow[g] = (const int4v*)(adj + (size_t)row[g] * GN);
  }

  const int CW = GN / NCH;                  // 2048 columns per chunk
  const int j0 = chunk * CW;
  const float4* __restrict__ fdv  = (const float4*)fd2;
  const short8* __restrict__ wpk8 = (const short8*)wpk;

  f32x4 acc[4][4];
  f32x4 accd[4];
#pragma unroll
  for (int g = 0; g < 4; ++g) {
    accd[g] = (f32x4){0.f, 0.f, 0.f, 0.f};
#pragma unroll
    for (int b = 0; b < 4; ++b) acc[g][b] = (f32x4){0.f, 0.f, 0.f, 0.f};
  }

  short8 b_ones;
#pragma unroll
  for (int i = 0; i < 8; ++i) b_ones[i] = (short)0x3F80;  // bf16 1.0

  auto pcalc = [&](int a, float fd, float fsv) -> unsigned short {
    float sv = fsv + fd;
    float lv = fmaxf(sv, 0.02f * sv);       // lrelu (commutes with *log2e)
    float pe = __builtin_amdgcn_exp2f(lv);
    pe = (a != 0) ? pe : 0.f;
    return f2bf(pe);
  };

  auto mk_af = [&](int4v aA, int4v aB, float4 fA, float4 fB, float fsv) -> short8 {
    short8 af;
    af[0] = (short)pcalc(aA.x, fA.x, fsv);
    af[1] = (short)pcalc(aA.y, fA.y, fsv);
    af[2] = (short)pcalc(aA.z, fA.z, fsv);
    af[3] = (short)pcalc(aA.w, fA.w, fsv);
    af[4] = (short)pcalc(aB.x, fB.x, fsv);
    af[5] = (short)pcalc(aB.y, fB.y, fsv);
    af[6] = (short)pcalc(aB.z, fB.z, fsv);
    af[7] = (short)pcalc(aB.w, fB.w, fsv);
    return af;
  };

#pragma unroll 1
  for (int j = j0; j < j0 + CW; j += 32) {
    const int i4 = (j >> 2) + (q << 1);

    // adj: 8 nontemporal 16B loads (4 row groups x 2)
    int4v a0[4], a1[4];
#pragma unroll
    for (int g = 0; g < 4; ++g) {
      a0[g] = __builtin_nontemporal_load(arow[g] + i4);
      a1[g] = __builtin_nontemporal_load(arow[g] + i4 + 1);
    }
    float4 f0 = fdv[i4];
    float4 f1 = fdv[i4 + 1];

    // packed B fragments: 4 contiguous 1 KB wave-loads, shared by 4 A-frags
    const short8* wb = wpk8 + (size_t)(j >> 5) * 512 + lane;
    short8 b0 = wb[0];
    short8 b1 = wb[128];
    short8 b2 = wb[256];
    short8 b3 = wb[384];

#pragma unroll
    for (int g = 0; g < 4; ++g) {
      short8 af = mk_af(a0[g], a1[g], f0, f1, fs[g]);
      acc[g][0] = __builtin_amdgcn_mfma_f32_16x16x32_bf16(af, b0, acc[g][0], 0, 0, 0);
      acc[g][1] = __builtin_amdgcn_mfma_f32_16x16x32_bf16(af, b1, acc[g][1], 0, 0, 0);
      acc[g][2] = __builtin_amdgcn_mfma_f32_16x16x32_bf16(af, b2, acc[g][2], 0, 0, 0);
      acc[g][3] = __builtin_amdgcn_mfma_f32_16x16x32_bf16(af, b3, acc[g][3], 0, 0, 0);
      accd[g]   = __builtin_amdgcn_mfma_f32_16x16x32_bf16(af, b_ones, accd[g], 0, 0, 0);
    }
  }

  // epilogue: plain stores into this chunk's private slab (no atomics)
  float* np = nump + (size_t)chunk * GN * GOUT;
  float* dp = denp + (size_t)chunk * GN;
#pragma unroll
  for (int g = 0; g < 4; ++g) {
    const int orow0 = strip * 64 + g * 16 + q * 4;   // C/D: row = q*4+r, col = m
#pragma unroll
    for (int r = 0; r < 4; ++r) {
      float* nr = np + (size_t)(orow0 + r) * GOUT + m;
      __builtin_nontemporal_store(acc[g][0][r], nr + 0);
      __builtin_nontemporal_store(acc[g][1][r], nr + 16);
      __builtin_nontemporal_store(acc[g][2][r], nr + 32);
      __builtin_nontemporal_store(acc[g][3][r], nr + 48);
      if (m == 0) dp[orow0 + r] = accd[g][r];   // col-independent for B=ones
    }
  }
}

// ---------------------------------------------------------------------------
// finalize: out = elu( (sum_c num_c) / (sum_c den_c) )
// ---------------------------------------------------------------------------
__global__ __launch_bounds__(256) void fin_kernel(
    const float* __restrict__ nump, const float* __restrict__ denp,
    float* __restrict__ out)
{
  const int g = blockIdx.x * 256 + threadIdx.x;
  if (g >= GN * GOUT) return;
  const int row = g >> 6;
  float s = 0.f, d = 0.f;
#pragma unroll
  for (int c = 0; c < NCH; ++c) {
    s += nump[(size_t)c * GN * GOUT + g];
    d += denp[(size_t)c * GN + row];
  }
  float v = s / d;
  out[g] = (v > 0.f) ? v : expm1f(v);
}

extern "C" void kernel_launch(void* const* d_in, const int* in_sizes, int n_in,
                              void* d_out, int out_size, void* d_ws, size_t ws_size,
                              hipStream_t stream) {
  const float* x   = (const float*)d_in[0];
  const int*   adj = (const int*)d_in[1];
  const float* w   = (const float*)d_in[2];
  const float* aw  = (const float*)d_in[3];
  float* out = (float*)d_out;

  // ws layout (floats): nump[8*N*64] | denp[8*N] | fs2[N] | fd2[N] | wpk(bf16 64*N)
  float* nump = (float*)d_ws;
  float* denp = nump + (size_t)NCH * GN * GOUT;
  float* fs2  = denp + (size_t)NCH * GN;
  float* fd2  = fs2 + GN;
  unsigned short* wpk = (unsigned short*)(fd2 + GN);
  // ~37 MB of the ws; everything fully written before read -> no memset needed

  prep_kernel<<<GN / 64, 256, 0, stream>>>(x, w, aw, wpk, fs2, fd2);
  gat_main<<<(GN / 64) * NCH / 4, 256, 0, stream>>>(adj, wpk, fs2, fd2, nump, denp);
  fin_kernel<<<(GN * GOUT) / 256, 256, 0, stream>>>(nump, denp, out);
}